// Round 3
// baseline (2641.483 us; speedup 1.0000x reference)
//
#include <hip/hip_runtime.h>

typedef unsigned short u16;
typedef unsigned int u32;
typedef short short8 __attribute__((ext_vector_type(8)));
typedef float float4v __attribute__((ext_vector_type(4)));

#define L_SEQ 1024
#define NB 4
#define NH 16
#define DK 128
#define DV 128
#define HID 2048
#define NQKVZ 8192
#define CONV_DIM 6144

static __device__ __forceinline__ float bf2f(u16 u) {
    union { u32 i; float f; } x; x.i = ((u32)u) << 16; return x.f;
}
static __device__ __forceinline__ u16 f2bf(float f) {
    union { float f; u32 u; } x; x.f = f;
    u32 r = x.u + 0x7FFF + ((x.u >> 16) & 1);
    return (u16)(r >> 16);
}

// ---------------- fp32 -> bf16 elementwise convert ---------------------------
__global__ __launch_bounds__(256) void f32_to_bf16(
    const float* __restrict__ in, u16* __restrict__ out) {
    long i = ((long)blockIdx.x * 256 + threadIdx.x) * 8;
    float4 a = *(const float4*)(in + i);
    float4 b = *(const float4*)(in + i + 4);
    u16 tmp[8];
    tmp[0] = f2bf(a.x); tmp[1] = f2bf(a.y); tmp[2] = f2bf(a.z); tmp[3] = f2bf(a.w);
    tmp[4] = f2bf(b.x); tmp[5] = f2bf(b.y); tmp[6] = f2bf(b.z); tmp[7] = f2bf(b.w);
    *(uint4*)(out + i) = *(const uint4*)tmp;
}

// ---------------- transpose fp32 (RxC) -> bf16 (CxR) -------------------------
__global__ __launch_bounds__(256) void transpose_f32_bf16(
    const float* __restrict__ in, u16* __restrict__ out, int R, int C) {
    __shared__ float tile[32][33];
    int bx = blockIdx.x, by = blockIdx.y;
    int c = threadIdx.x & 31;
    int r0 = threadIdx.x >> 5;
#pragma unroll
    for (int i = 0; i < 4; i++) {
        int r = r0 + i * 8;
        tile[r][c] = in[(long)(by * 32 + r) * C + bx * 32 + c];
    }
    __syncthreads();
#pragma unroll
    for (int i = 0; i < 4; i++) {
        int r = r0 + i * 8;
        out[(long)(bx * 32 + r) * R + by * 32 + c] = f2bf(tile[c][r]);
    }
}

// ---------------- transpose fp32 (RxC) -> fp32 (CxR) -------------------------
__global__ __launch_bounds__(256) void transpose_f32_f32(
    const float* __restrict__ in, float* __restrict__ out, int R, int C) {
    __shared__ float tile[32][33];
    int bx = blockIdx.x, by = blockIdx.y;
    int c = threadIdx.x & 31;
    int r0 = threadIdx.x >> 5;
#pragma unroll
    for (int i = 0; i < 4; i++) {
        int r = r0 + i * 8;
        tile[r][c] = in[(long)(by * 32 + r) * C + bx * 32 + c];
    }
    __syncthreads();
#pragma unroll
    for (int i = 0; i < 4; i++) {
        int r = r0 + i * 8;
        out[(long)(bx * 32 + r) * R + by * 32 + c] = tile[c][r];
    }
}

// ---------------- GEMM: C[M,N] = A[M,K] * BT[N,K]^T, bf16 in, OutT out -------
#define BM 128
#define BN 128
#define BKK 32
#define LDT 40  // padded LDS row stride (elements)

static __device__ __forceinline__ void store_out(u16* p, float v)  { *p = f2bf(v); }
static __device__ __forceinline__ void store_out(float* p, float v){ *p = v; }

template <typename OutT>
__global__ __launch_bounds__(256) void gemm_abT(
    const u16* __restrict__ A, const u16* __restrict__ BT,
    OutT* __restrict__ C, int M, int N, int K) {
    __shared__ u16 As[BM * LDT];
    __shared__ u16 Bs[BN * LDT];
    int t = threadIdx.x;
    int lane = t & 63;
    int w = t >> 6;
    int wm = (w & 1) * 64;
    int wn = (w >> 1) * 64;
    int l15 = lane & 15;
    int quad = lane >> 4;
    long blockM = (long)blockIdx.y * BM;
    long blockN = (long)blockIdx.x * BN;

    float4v acc[4][4];
#pragma unroll
    for (int i = 0; i < 4; i++)
#pragma unroll
        for (int j = 0; j < 4; j++) acc[i][j] = (float4v){0.f, 0.f, 0.f, 0.f};

    int ar0 = t >> 2, ac0 = (t & 3) * 8;
    int ar1 = (t + 256) >> 2, ac1 = ((t + 256) & 3) * 8;

    const u16* Ab = A + blockM * K;
    const u16* Bb = BT + blockN * K;

    for (int k0 = 0; k0 < K; k0 += BKK) {
        uint4 av0 = *(const uint4*)(Ab + (long)ar0 * K + k0 + ac0);
        uint4 av1 = *(const uint4*)(Ab + (long)ar1 * K + k0 + ac1);
        uint4 bv0 = *(const uint4*)(Bb + (long)ar0 * K + k0 + ac0);
        uint4 bv1 = *(const uint4*)(Bb + (long)ar1 * K + k0 + ac1);
        __syncthreads();  // previous iteration's LDS reads done
        *(uint2*)(As + ar0 * LDT + ac0)     = make_uint2(av0.x, av0.y);
        *(uint2*)(As + ar0 * LDT + ac0 + 4) = make_uint2(av0.z, av0.w);
        *(uint2*)(As + ar1 * LDT + ac1)     = make_uint2(av1.x, av1.y);
        *(uint2*)(As + ar1 * LDT + ac1 + 4) = make_uint2(av1.z, av1.w);
        *(uint2*)(Bs + ar0 * LDT + ac0)     = make_uint2(bv0.x, bv0.y);
        *(uint2*)(Bs + ar0 * LDT + ac0 + 4) = make_uint2(bv0.z, bv0.w);
        *(uint2*)(Bs + ar1 * LDT + ac1)     = make_uint2(bv1.x, bv1.y);
        *(uint2*)(Bs + ar1 * LDT + ac1 + 4) = make_uint2(bv1.z, bv1.w);
        __syncthreads();

        union { short8 v; uint2 u[2]; } fa[4], fb[4];
#pragma unroll
        for (int i = 0; i < 4; i++) {
            const u16* pa = As + (wm + i * 16 + l15) * LDT + quad * 8;
            fa[i].u[0] = *(const uint2*)pa;
            fa[i].u[1] = *(const uint2*)(pa + 4);
            const u16* pb = Bs + (wn + i * 16 + l15) * LDT + quad * 8;
            fb[i].u[0] = *(const uint2*)pb;
            fb[i].u[1] = *(const uint2*)(pb + 4);
        }
#pragma unroll
        for (int i = 0; i < 4; i++)
#pragma unroll
            for (int j = 0; j < 4; j++)
                acc[i][j] = __builtin_amdgcn_mfma_f32_16x16x32_bf16(
                    fa[i].v, fb[j].v, acc[i][j], 0, 0, 0);
    }

#pragma unroll
    for (int i = 0; i < 4; i++) {
        long mrow = blockM + wm + i * 16 + quad * 4;
#pragma unroll
        for (int j = 0; j < 4; j++) {
            long col = blockN + wn + j * 16 + l15;
#pragma unroll
            for (int r = 0; r < 4; r++) {
                store_out(&C[(mrow + r) * N + col], acc[i][j][r]);
            }
        }
    }
}

// ---------------- ba: eg = exp(g), beta = sigmoid(b) -------------------------
// NOTE: stores exp(g) directly so the scan has no expf on its critical path.
__global__ __launch_bounds__(64) void ba_kernel(
    const float* __restrict__ hs, const float* __restrict__ WbaT,
    const float* __restrict__ A_log, const float* __restrict__ dt_bias,
    float* __restrict__ egout, float* __restrict__ bout) {
    int bl = blockIdx.x;  // b*L + l
    int b = bl >> 10, l = bl & 1023;
    int t = threadIdx.x;
    __shared__ __align__(16) float hb[HID];
    const float* hrow = hs + (long)bl * HID;
#pragma unroll
    for (int i = 0; i < 8; i++) {
        int idx = (t + i * 64) * 4;
        *(float4*)(hb + idx) = *(const float4*)(hrow + idx);
    }
    __syncthreads();
    int n = t & 31, hf = t >> 5;
    const float* wrow = WbaT + (long)n * HID + hf * 1024;
    const float* hp = hb + hf * 1024;
    float acc = 0.f;
    for (int i = 0; i < 1024; i += 4) {
        float4 wv = *(const float4*)(wrow + i);
        float4 hv = *(const float4*)(hp + i);
        acc += wv.x * hv.x + wv.y * hv.y + wv.z * hv.z + wv.w * hv.w;
    }
    acc += __shfl_down(acc, 32);
    if (t < 32) {
        if (n < 16) {
            bout[((long)(b * NH + n)) * L_SEQ + l] = 1.f / (1.f + expf(-acc));
        } else {
            int h = n - 16;
            float x = acc + dt_bias[h];
            float sp = (x > 20.f) ? x : log1pf(expf(x));
            egout[((long)(b * NH + h)) * L_SEQ + l] = expf(-expf(A_log[h]) * sp);
        }
    }
}

// ---------------- conv(KS=4 causal depthwise) + l2norm(q,k) + split v --------
__global__ __launch_bounds__(256) void conv_qkv(
    const u16* __restrict__ qkvz, const float* __restrict__ conv_w,
    const float* __restrict__ conv_b,
    float* __restrict__ qs, float* __restrict__ ks, float* __restrict__ vs) {
    int bl = blockIdx.x;  // b*L + l
    int b = bl >> 10, l = bl & 1023;
    int t = threadIdx.x;
    __shared__ float xb[CONV_DIM];
    __shared__ float red[32][9];
    __shared__ float rbuf[32];

    for (int c = t; c < CONV_DIM; c += 256) {
        float acc = conv_b[c];
        float w0 = conv_w[c * 4 + 0];
        float w1 = conv_w[c * 4 + 1];
        float w2 = conv_w[c * 4 + 2];
        float w3 = conv_w[c * 4 + 3];
        long rowbase = (long)(b * L_SEQ) * NQKVZ + c;
        if (l - 3 >= 0) acc += bf2f(qkvz[rowbase + (long)(l - 3) * NQKVZ]) * w0;
        if (l - 2 >= 0) acc += bf2f(qkvz[rowbase + (long)(l - 2) * NQKVZ]) * w1;
        if (l - 1 >= 0) acc += bf2f(qkvz[rowbase + (long)(l - 1) * NQKVZ]) * w2;
        acc += bf2f(qkvz[rowbase + (long)l * NQKVZ]) * w3;
        xb[c] = acc;
    }
    __syncthreads();
    {
        int grp = t >> 3;   // 0..31 (q heads 0..15, k heads 16..31)
        int j8 = t & 7;
        float s = 0.f;
#pragma unroll
        for (int i = 0; i < 16; i++) {
            float xv = xb[grp * 128 + j8 * 16 + i];
            s += xv * xv;
        }
        red[grp][j8] = s;
    }
    __syncthreads();
    if (t < 32) {
        float s = 0.f;
#pragma unroll
        for (int i = 0; i < 8; i++) s += red[t][i];
        rbuf[t] = rsqrtf(s + 1e-6f);
    }
    __syncthreads();
    for (int c = t; c < CONV_DIM; c += 256) {
        float xv = xb[c];
        if (c < 2048) {
            int h = c >> 7, d = c & 127;
            qs[(((long)(b * NH + h)) * L_SEQ + l) * DK + d] = xv * rbuf[h];
        } else if (c < 4096) {
            int c2 = c - 2048;
            int h = c2 >> 7, d = c2 & 127;
            ks[(((long)(b * NH + h)) * L_SEQ + l) * DK + d] = xv * rbuf[16 + h];
        } else {
            int c2 = c - 4096;
            int h = c2 >> 7, d = c2 & 127;
            vs[(((long)(b * NH + h)) * L_SEQ + l) * DV + d] = xv;
        }
    }
}

// ---------------- sequential gated delta scan, v2 ----------------------------
// 512 blocks: bh = bid>>3 (b*16+h), dc = bid&7 (16 d-columns per block).
// 256 threads: lane = t&63, kg = lane&15 (16 k-groups x 8), dlw = lane>>4,
// d = dc*16 + (t>>6)*4 + dlw. Explicit pairwise trees; 4-lane xor reduce;
// exp(g) precomputed; prefetch distance 2 in registers. No barriers.
__global__ __launch_bounds__(256) void gdn_scan(
    const float* __restrict__ q, const float* __restrict__ k,
    const float* __restrict__ v, const float* __restrict__ eg,
    const float* __restrict__ beta, float* __restrict__ o) {
    int bid = blockIdx.x;
    int dc = bid & 7;
    int bh = bid >> 3;          // b*NH + h
    int b = bh >> 4, h = bh & 15;
    int t = threadIdx.x;
    int lane = t & 63;
    int kg = lane & 15;
    int d = dc * 16 + (t >> 6) * 4 + (lane >> 4);

    const long base = (long)bh * L_SEQ;
    const float* kp = k + base * DK + kg * 8;
    const float* qp = q + base * DK + kg * 8;
    const float* vp = v + base * DV + d;
    const float* ep = eg + base;
    const float* bp = beta + base;
    const float scale = 0.08838834764831845f;  // 128^-0.5

    float S[8];
#pragma unroll
    for (int j = 0; j < 8; j++) S[j] = 0.f;

    // prefetch ring, distance 2
    float4 kA[2], kB[2], qA[2], qB[2];
    float vv[2], ev[2], bv[2];
#pragma unroll
    for (int s = 0; s < 2; s++) {
        long row = (long)s * DK;
        kA[s] = *(const float4*)(kp + row);
        kB[s] = *(const float4*)(kp + row + 4);
        qA[s] = *(const float4*)(qp + row);
        qB[s] = *(const float4*)(qp + row + 4);
        vv[s] = vp[(long)s * DV];
        ev[s] = ep[s];
        bv[s] = bp[s];
    }

    for (int ts = 0; ts < L_SEQ; ts++) {
        int cur = ts & 1;
        float kf[8] = {kA[cur].x, kA[cur].y, kA[cur].z, kA[cur].w,
                       kB[cur].x, kB[cur].y, kB[cur].z, kB[cur].w};
        float qf[8] = {qA[cur].x, qA[cur].y, qA[cur].z, qA[cur].w,
                       qB[cur].x, qB[cur].y, qB[cur].z, qB[cur].w};
        float e = ev[cur], bt = bv[cur], vval = vv[cur];
        if (ts + 2 < L_SEQ) {  // refill slot just vacated
            long row = (long)(ts + 2) * DK;
            kA[cur] = *(const float4*)(kp + row);
            kB[cur] = *(const float4*)(kp + row + 4);
            qA[cur] = *(const float4*)(qp + row);
            qB[cur] = *(const float4*)(qp + row + 4);
            vv[cur] = vp[(long)(ts + 2) * DV];
            ev[cur] = ep[ts + 2];
            bv[cur] = bp[ts + 2];
        }
        // S' = S * e ; p = sum_j kf[j]*S'[j]  (explicit tree)
        float pr[8];
#pragma unroll
        for (int j = 0; j < 8; j++) {
            S[j] *= e;
            pr[j] = kf[j] * S[j];
        }
        float p01 = pr[0] + pr[1], p23 = pr[2] + pr[3];
        float p45 = pr[4] + pr[5], p67 = pr[6] + pr[7];
        float p = (p01 + p23) + (p45 + p67);
        p += __shfl_xor(p, 1);
        p += __shfl_xor(p, 2);
        p += __shfl_xor(p, 4);
        p += __shfl_xor(p, 8);
        float delta = (vval - p) * bt;
        // S += k*delta ; oo = sum_j qf[j]*S[j]
        float orr[8];
#pragma unroll
        for (int j = 0; j < 8; j++) {
            S[j] = fmaf(kf[j], delta, S[j]);
            orr[j] = qf[j] * S[j];
        }
        float o01 = orr[0] + orr[1], o23 = orr[2] + orr[3];
        float o45 = orr[4] + orr[5], o67 = orr[6] + orr[7];
        float oo = (o01 + o23) + (o45 + o67);
        oo += __shfl_xor(oo, 1);
        oo += __shfl_xor(oo, 2);
        oo += __shfl_xor(oo, 4);
        oo += __shfl_xor(oo, 8);
        if (kg == 0) {
            o[(((long)(b * L_SEQ + ts)) * NH + h) * DV + d] = oo * scale;
        }
    }
}

// ---------------- gated RMS norm -> bf16 A2 ----------------------------------
__global__ __launch_bounds__(128) void gated_norm(
    const float* __restrict__ o, const u16* __restrict__ qkvz,
    const float* __restrict__ norm_w, u16* __restrict__ A2) {
    int bid = blockIdx.x;  // (b*L+l)*16 + h
    int t = threadIdx.x;   // 0..127
    float ov = o[(long)bid * 128 + t];
    float s = ov * ov;
#pragma unroll
    for (int off = 32; off > 0; off >>= 1) s += __shfl_down(s, off);
    __shared__ float ws2[2];
    if ((t & 63) == 0) ws2[t >> 6] = s;
    __syncthreads();
    float tot = ws2[0] + ws2[1];
    float rinv = rsqrtf(tot * (1.f / 128.f) + 1e-6f);
    int bl = bid >> 4, h = bid & 15;
    float z = bf2f(qkvz[(long)bl * NQKVZ + CONV_DIM + h * 128 + t]);
    float sig = 1.f / (1.f + expf(-z));
    float val = ov * rinv * norm_w[t] * sig;
    A2[(long)bl * 2048 + h * 128 + t] = f2bf(val);
}

// ---------------- host-side launcher -----------------------------------------
extern "C" void kernel_launch(void* const* d_in, const int* in_sizes, int n_in,
                              void* d_out, int out_size, void* d_ws, size_t ws_size,
                              hipStream_t stream) {
    const float* hs    = (const float*)d_in[0];  // (4,1024,2048)
    const float* Wqkvz = (const float*)d_in[1];  // (2048,8192)
    const float* Wba   = (const float*)d_in[2];  // (2048,32)
    const float* convw = (const float*)d_in[3];  // (6144,4)
    const float* convb = (const float*)d_in[4];  // (6144,)
    const float* A_log = (const float*)d_in[5];  // (16,)
    const float* dtb   = (const float*)d_in[6];  // (16,)
    const float* normw = (const float*)d_in[7];  // (128,)
    const float* Wout  = (const float*)d_in[8];  // (2048,2048)

    char* ws = (char*)d_ws;
    size_t off = 0;
    auto alloc = [&](size_t bytes) {
        size_t o = off;
        off = (off + bytes + 255) & ~(size_t)255;
        return o;
    };
    // region0: WqkvzT (bf16, 32MB) — dead after GEMM1, reused for os (fp32, 32MB)
    size_t r0 = alloc((size_t)NQKVZ * HID * 2);
    // region1: hs_bf16 (16MB) — dead after GEMM1, reused for A2 (bf16, 16MB)
    size_t r1 = alloc((size_t)4096 * HID * 2);
    u16*   WqkvzT = (u16*)(ws + r0);
    float* os     = (float*)(ws + r0);
    u16*   hsb    = (u16*)(ws + r1);
    u16*   A2     = (u16*)(ws + r1);
    u16*   qkvz   = (u16*)(ws + alloc((size_t)4096 * NQKVZ * 2));
    float* qs     = (float*)(ws + alloc((size_t)4096 * 2048 * 4));
    float* ks     = (float*)(ws + alloc((size_t)4096 * 2048 * 4));
    float* vs     = (float*)(ws + alloc((size_t)4096 * 2048 * 4));
    float* egs    = (float*)(ws + alloc((size_t)NB * NH * L_SEQ * 4));
    float* bs     = (float*)(ws + alloc((size_t)NB * NH * L_SEQ * 4));
    u16*   WoutT  = (u16*)(ws + alloc((size_t)HID * 2048 * 2));
    float* WbaT   = (float*)(ws + alloc((size_t)32 * HID * 4));

    // 1. convert + transposes (fp32 -> bf16 weights/activations)
    hipLaunchKernelGGL(f32_to_bf16, dim3(4096), dim3(256), 0, stream, hs, hsb);
    hipLaunchKernelGGL(transpose_f32_bf16, dim3(NQKVZ / 32, HID / 32), dim3(256), 0, stream,
                       Wqkvz, WqkvzT, HID, NQKVZ);
    hipLaunchKernelGGL(transpose_f32_bf16, dim3(2048 / 32, 2048 / 32), dim3(256), 0, stream,
                       Wout, WoutT, 2048, 2048);
    hipLaunchKernelGGL(transpose_f32_f32, dim3(1, HID / 32), dim3(256), 0, stream,
                       Wba, WbaT, HID, 32);

    // 2. big GEMM: qkvz = hs @ W_qkvz (bf16 in, bf16 out)
    hipLaunchKernelGGL((gemm_abT<u16>), dim3(NQKVZ / BN, 4096 / BM), dim3(256), 0, stream,
                       hsb, WqkvzT, qkvz, 4096, NQKVZ, HID);

    // 3. ba -> exp(g), beta (pure fp32)
    hipLaunchKernelGGL(ba_kernel, dim3(4096), dim3(64), 0, stream,
                       hs, WbaT, A_log, dtb, egs, bs);

    // 4. conv + l2norm -> q,k,v (fp32)
    hipLaunchKernelGGL(conv_qkv, dim3(4096), dim3(256), 0, stream,
                       qkvz, convw, convb, qs, ks, vs);

    // 5. scan (fp32, barrier-free, tree-reduced, prefetch-2)
    hipLaunchKernelGGL(gdn_scan, dim3(NB * NH * 8), dim3(256), 0, stream,
                       qs, ks, vs, egs, bs, os);

    // 6. gated RMS norm -> bf16 A2
    hipLaunchKernelGGL(gated_norm, dim3(4096 * NH), dim3(128), 0, stream,
                       os, qkvz, normw, A2);

    // 7. out = A2 @ W_out (bf16 in, fp32 out)
    hipLaunchKernelGGL((gemm_abT<float>), dim3(2048 / BN, 4096 / BM), dim3(256), 0, stream,
                       A2, WoutT, (float*)d_out, 4096, 2048, HID);
}

// Round 4
// 947.900 us; speedup vs baseline: 2.7867x; 2.7867x over previous
//
#include <hip/hip_runtime.h>

typedef unsigned short u16;
typedef unsigned int u32;
typedef short short8 __attribute__((ext_vector_type(8)));
typedef float float4v __attribute__((ext_vector_type(4)));

#define L_SEQ 1024
#define NB 4
#define NH 16
#define DK 128
#define DV 128
#define HID 2048
#define NQKVZ 8192
#define CONV_DIM 6144

static __device__ __forceinline__ float bf2f(u16 u) {
    union { u32 i; float f; } x; x.i = ((u32)u) << 16; return x.f;
}
static __device__ __forceinline__ u16 f2bf(float f) {
    union { float f; u32 u; } x; x.f = f;
    u32 r = x.u + 0x7FFF + ((x.u >> 16) & 1);
    return (u16)(r >> 16);
}

// DPP cross-lane adds (pure VALU, no DS): xor1, xor2 within quad; half-mirror
// covers lane^4 once quads are uniform. Sum over 8 adjacent lanes in 3 adds.
#define DPP_ADD(x, ctrl) \
    ((x) + __int_as_float(__builtin_amdgcn_update_dpp( \
         0, __float_as_int(x), (ctrl), 0xF, 0xF, true)))
static __device__ __forceinline__ float sum8_dpp(float x) {
    x = DPP_ADD(x, 0xB1);   // quad_perm [1,0,3,2]  = lane^1
    x = DPP_ADD(x, 0x4E);   // quad_perm [2,3,0,1]  = lane^2
    x = DPP_ADD(x, 0x141);  // row_half_mirror      = cross-quad within 8
    return x;
}

// ---------------- fp32 -> bf16 elementwise convert ---------------------------
__global__ __launch_bounds__(256) void f32_to_bf16(
    const float* __restrict__ in, u16* __restrict__ out) {
    long i = ((long)blockIdx.x * 256 + threadIdx.x) * 8;
    float4 a = *(const float4*)(in + i);
    float4 b = *(const float4*)(in + i + 4);
    u16 tmp[8];
    tmp[0] = f2bf(a.x); tmp[1] = f2bf(a.y); tmp[2] = f2bf(a.z); tmp[3] = f2bf(a.w);
    tmp[4] = f2bf(b.x); tmp[5] = f2bf(b.y); tmp[6] = f2bf(b.z); tmp[7] = f2bf(b.w);
    *(uint4*)(out + i) = *(const uint4*)tmp;
}

// ---------------- transpose fp32 (RxC) -> bf16 (CxR) -------------------------
__global__ __launch_bounds__(256) void transpose_f32_bf16(
    const float* __restrict__ in, u16* __restrict__ out, int R, int C) {
    __shared__ float tile[32][33];
    int bx = blockIdx.x, by = blockIdx.y;
    int c = threadIdx.x & 31;
    int r0 = threadIdx.x >> 5;
#pragma unroll
    for (int i = 0; i < 4; i++) {
        int r = r0 + i * 8;
        tile[r][c] = in[(long)(by * 32 + r) * C + bx * 32 + c];
    }
    __syncthreads();
#pragma unroll
    for (int i = 0; i < 4; i++) {
        int r = r0 + i * 8;
        out[(long)(bx * 32 + r) * R + by * 32 + c] = f2bf(tile[c][r]);
    }
}

// ---------------- transpose fp32 (RxC) -> fp32 (CxR) -------------------------
__global__ __launch_bounds__(256) void transpose_f32_f32(
    const float* __restrict__ in, float* __restrict__ out, int R, int C) {
    __shared__ float tile[32][33];
    int bx = blockIdx.x, by = blockIdx.y;
    int c = threadIdx.x & 31;
    int r0 = threadIdx.x >> 5;
#pragma unroll
    for (int i = 0; i < 4; i++) {
        int r = r0 + i * 8;
        tile[r][c] = in[(long)(by * 32 + r) * C + bx * 32 + c];
    }
    __syncthreads();
#pragma unroll
    for (int i = 0; i < 4; i++) {
        int r = r0 + i * 8;
        out[(long)(bx * 32 + r) * R + by * 32 + c] = tile[c][r];
    }
}

// ---------------- GEMM: C[M,N] = A[M,K] * BT[N,K]^T, bf16 in, OutT out -------
#define BM 128
#define BN 128
#define BKK 32
#define LDT 40  // padded LDS row stride (elements)

static __device__ __forceinline__ void store_out(u16* p, float v)  { *p = f2bf(v); }
static __device__ __forceinline__ void store_out(float* p, float v){ *p = v; }

template <typename OutT>
__global__ __launch_bounds__(256) void gemm_abT(
    const u16* __restrict__ A, const u16* __restrict__ BT,
    OutT* __restrict__ C, int M, int N, int K) {
    __shared__ u16 As[BM * LDT];
    __shared__ u16 Bs[BN * LDT];
    int t = threadIdx.x;
    int lane = t & 63;
    int w = t >> 6;
    int wm = (w & 1) * 64;
    int wn = (w >> 1) * 64;
    int l15 = lane & 15;
    int quad = lane >> 4;
    long blockM = (long)blockIdx.y * BM;
    long blockN = (long)blockIdx.x * BN;

    float4v acc[4][4];
#pragma unroll
    for (int i = 0; i < 4; i++)
#pragma unroll
        for (int j = 0; j < 4; j++) acc[i][j] = (float4v){0.f, 0.f, 0.f, 0.f};

    int ar0 = t >> 2, ac0 = (t & 3) * 8;
    int ar1 = (t + 256) >> 2, ac1 = ((t + 256) & 3) * 8;

    const u16* Ab = A + blockM * K;
    const u16* Bb = BT + blockN * K;

    for (int k0 = 0; k0 < K; k0 += BKK) {
        uint4 av0 = *(const uint4*)(Ab + (long)ar0 * K + k0 + ac0);
        uint4 av1 = *(const uint4*)(Ab + (long)ar1 * K + k0 + ac1);
        uint4 bv0 = *(const uint4*)(Bb + (long)ar0 * K + k0 + ac0);
        uint4 bv1 = *(const uint4*)(Bb + (long)ar1 * K + k0 + ac1);
        __syncthreads();  // previous iteration's LDS reads done
        *(uint2*)(As + ar0 * LDT + ac0)     = make_uint2(av0.x, av0.y);
        *(uint2*)(As + ar0 * LDT + ac0 + 4) = make_uint2(av0.z, av0.w);
        *(uint2*)(As + ar1 * LDT + ac1)     = make_uint2(av1.x, av1.y);
        *(uint2*)(As + ar1 * LDT + ac1 + 4) = make_uint2(av1.z, av1.w);
        *(uint2*)(Bs + ar0 * LDT + ac0)     = make_uint2(bv0.x, bv0.y);
        *(uint2*)(Bs + ar0 * LDT + ac0 + 4) = make_uint2(bv0.z, bv0.w);
        *(uint2*)(Bs + ar1 * LDT + ac1)     = make_uint2(bv1.x, bv1.y);
        *(uint2*)(Bs + ar1 * LDT + ac1 + 4) = make_uint2(bv1.z, bv1.w);
        __syncthreads();

        union { short8 v; uint2 u[2]; } fa[4], fb[4];
#pragma unroll
        for (int i = 0; i < 4; i++) {
            const u16* pa = As + (wm + i * 16 + l15) * LDT + quad * 8;
            fa[i].u[0] = *(const uint2*)pa;
            fa[i].u[1] = *(const uint2*)(pa + 4);
            const u16* pb = Bs + (wn + i * 16 + l15) * LDT + quad * 8;
            fb[i].u[0] = *(const uint2*)pb;
            fb[i].u[1] = *(const uint2*)(pb + 4);
        }
#pragma unroll
        for (int i = 0; i < 4; i++)
#pragma unroll
            for (int j = 0; j < 4; j++)
                acc[i][j] = __builtin_amdgcn_mfma_f32_16x16x32_bf16(
                    fa[i].v, fb[j].v, acc[i][j], 0, 0, 0);
    }

#pragma unroll
    for (int i = 0; i < 4; i++) {
        long mrow = blockM + wm + i * 16 + quad * 4;
#pragma unroll
        for (int j = 0; j < 4; j++) {
            long col = blockN + wn + j * 16 + l15;
#pragma unroll
            for (int r = 0; r < 4; r++) {
                store_out(&C[(mrow + r) * N + col], acc[i][j][r]);
            }
        }
    }
}

// ---------------- ba: eg = exp(g), beta = sigmoid(b) -------------------------
__global__ __launch_bounds__(64) void ba_kernel(
    const float* __restrict__ hs, const float* __restrict__ WbaT,
    const float* __restrict__ A_log, const float* __restrict__ dt_bias,
    float* __restrict__ egout, float* __restrict__ bout) {
    int bl = blockIdx.x;  // b*L + l
    int b = bl >> 10, l = bl & 1023;
    int t = threadIdx.x;
    __shared__ __align__(16) float hb[HID];
    const float* hrow = hs + (long)bl * HID;
#pragma unroll
    for (int i = 0; i < 8; i++) {
        int idx = (t + i * 64) * 4;
        *(float4*)(hb + idx) = *(const float4*)(hrow + idx);
    }
    __syncthreads();
    int n = t & 31, hf = t >> 5;
    const float* wrow = WbaT + (long)n * HID + hf * 1024;
    const float* hp = hb + hf * 1024;
    float acc = 0.f;
    for (int i = 0; i < 1024; i += 4) {
        float4 wv = *(const float4*)(wrow + i);
        float4 hv = *(const float4*)(hp + i);
        acc += wv.x * hv.x + wv.y * hv.y + wv.z * hv.z + wv.w * hv.w;
    }
    acc += __shfl_down(acc, 32);
    if (t < 32) {
        if (n < 16) {
            bout[((long)(b * NH + n)) * L_SEQ + l] = 1.f / (1.f + expf(-acc));
        } else {
            int h = n - 16;
            float x = acc + dt_bias[h];
            float sp = (x > 20.f) ? x : log1pf(expf(x));
            egout[((long)(b * NH + h)) * L_SEQ + l] = expf(-expf(A_log[h]) * sp);
        }
    }
}

// ---------------- conv(KS=4 causal depthwise) + l2norm(q,k) + split v --------
__global__ __launch_bounds__(256) void conv_qkv(
    const u16* __restrict__ qkvz, const float* __restrict__ conv_w,
    const float* __restrict__ conv_b,
    float* __restrict__ qs, float* __restrict__ ks, float* __restrict__ vs) {
    int bl = blockIdx.x;  // b*L + l
    int b = bl >> 10, l = bl & 1023;
    int t = threadIdx.x;
    __shared__ float xb[CONV_DIM];
    __shared__ float red[32][9];
    __shared__ float rbuf[32];

    for (int c = t; c < CONV_DIM; c += 256) {
        float acc = conv_b[c];
        float w0 = conv_w[c * 4 + 0];
        float w1 = conv_w[c * 4 + 1];
        float w2 = conv_w[c * 4 + 2];
        float w3 = conv_w[c * 4 + 3];
        long rowbase = (long)(b * L_SEQ) * NQKVZ + c;
        if (l - 3 >= 0) acc += bf2f(qkvz[rowbase + (long)(l - 3) * NQKVZ]) * w0;
        if (l - 2 >= 0) acc += bf2f(qkvz[rowbase + (long)(l - 2) * NQKVZ]) * w1;
        if (l - 1 >= 0) acc += bf2f(qkvz[rowbase + (long)(l - 1) * NQKVZ]) * w2;
        acc += bf2f(qkvz[rowbase + (long)l * NQKVZ]) * w3;
        xb[c] = acc;
    }
    __syncthreads();
    {
        int grp = t >> 3;   // 0..31 (q heads 0..15, k heads 16..31)
        int j8 = t & 7;
        float s = 0.f;
#pragma unroll
        for (int i = 0; i < 16; i++) {
            float xv = xb[grp * 128 + j8 * 16 + i];
            s += xv * xv;
        }
        red[grp][j8] = s;
    }
    __syncthreads();
    if (t < 32) {
        float s = 0.f;
#pragma unroll
        for (int i = 0; i < 8; i++) s += red[t][i];
        rbuf[t] = rsqrtf(s + 1e-6f);
    }
    __syncthreads();
    for (int c = t; c < CONV_DIM; c += 256) {
        float xv = xb[c];
        if (c < 2048) {
            int h = c >> 7, d = c & 127;
            qs[(((long)(b * NH + h)) * L_SEQ + l) * DK + d] = xv * rbuf[h];
        } else if (c < 4096) {
            int c2 = c - 2048;
            int h = c2 >> 7, d = c2 & 127;
            ks[(((long)(b * NH + h)) * L_SEQ + l) * DK + d] = xv * rbuf[16 + h];
        } else {
            int c2 = c - 4096;
            int h = c2 >> 7, d = c2 & 127;
            vs[(((long)(b * NH + h)) * L_SEQ + l) * DV + d] = xv;
        }
    }
}

// ---------------- sequential gated delta scan, v4 ----------------------------
// 256 blocks = bh(64) x dc(4). 256 threads = 4 waves; per wave: kg = lane&7
// (16 k each), dw = lane>>3 (8 d-cols). LDS tiles of 64 timesteps staged with
// coalesced float4 loads (2 barriers / 64 steps). k/q LDS layout XOR-swizzled
// (chunk' = (chunk+kg)&3) -> 2-way conflicts only. Cross-lane k-reduction via
// 3 DPP adds (no DS on critical path). All private arrays constant-indexed.
#define SCAN_T 64

union F16u { float4 v4[4]; float f[16]; };

__global__ __launch_bounds__(256) void gdn_scan(
    const float* __restrict__ q, const float* __restrict__ k,
    const float* __restrict__ v, const float* __restrict__ eg,
    const float* __restrict__ beta, float* __restrict__ o) {
    int bid = blockIdx.x;
    int dc = bid & 3;
    int bh = bid >> 2;          // b*NH + h
    int b = bh >> 4, h = bh & 15;
    int t = threadIdx.x;
    int lane = t & 63;
    int wv = t >> 6;            // wave 0..3
    int kg = lane & 7;          // 16 k values per thread
    int dw = lane >> 3;         // 0..7
    int dl = wv * 8 + dw;       // 0..31
    int d = dc * 32 + dl;

    __shared__ float kt[SCAN_T * 128];
    __shared__ float qt[SCAN_T * 128];
    __shared__ float vt[SCAN_T * 32];
    __shared__ float et[SCAN_T];
    __shared__ float bts[SCAN_T];

    const long base = (long)bh * L_SEQ;
    const float* kgl = k + base * DK;
    const float* qgl = q + base * DK;
    const float* vgl = v + base * DV + dc * 32;
    const float* ep  = eg + base;
    const float* bp  = beta + base;
    const float scale = 0.08838834764831845f;  // 128^-0.5

    float S[16];
#pragma unroll
    for (int j = 0; j < 16; j++) S[j] = 0.f;

    // LDS read base for this thread's k-fragment (float index, pre-swizzle)
    const int frag_base = kg * 16;

    F16u KA, QA, KB, QB;

    auto load_frag = [&](F16u& KF, F16u& QF, int lt) {
        int rb = lt * 128 + frag_base;
#pragma unroll
        for (int i = 0; i < 4; i++) {
            int sw = ((i + kg) & 3) * 4;
            KF.v4[i] = *(const float4*)&kt[rb + sw];
            QF.v4[i] = *(const float4*)&qt[rb + sw];
        }
    };

    auto step = [&](const F16u& KF, const F16u& QF, int lt, int abs_ts) {
        float e = et[lt];
        float btv = bts[lt];
        float vval = vt[lt * 32 + dl];
        float pr[16];
#pragma unroll
        for (int j = 0; j < 16; j++) {
            S[j] *= e;
            pr[j] = KF.f[j] * S[j];
        }
        float p = ((pr[0] + pr[1]) + (pr[2] + pr[3])) +
                  ((pr[4] + pr[5]) + (pr[6] + pr[7])) +
                  (((pr[8] + pr[9]) + (pr[10] + pr[11])) +
                   ((pr[12] + pr[13]) + (pr[14] + pr[15])));
        p = sum8_dpp(p);
        float delta = (vval - p) * btv;
        float orr[16];
#pragma unroll
        for (int j = 0; j < 16; j++) {
            S[j] = fmaf(KF.f[j], delta, S[j]);
            orr[j] = QF.f[j] * S[j];
        }
        float oo = ((orr[0] + orr[1]) + (orr[2] + orr[3])) +
                   ((orr[4] + orr[5]) + (orr[6] + orr[7])) +
                   (((orr[8] + orr[9]) + (orr[10] + orr[11])) +
                    ((orr[12] + orr[13]) + (orr[14] + orr[15])));
        oo = sum8_dpp(oo);
        if (kg == 0) {
            o[(((long)(b * L_SEQ + abs_ts)) * NH + h) * DV + d] = oo * scale;
        }
    };

    for (int ts0 = 0; ts0 < L_SEQ; ts0 += SCAN_T) {
        __syncthreads();  // prior tile's LDS reads complete
        // ---- stage k, q (linear global -> swizzled LDS) ----
        {
            const float* ksrc = kgl + (long)ts0 * DK;
            const float* qsrc = qgl + (long)ts0 * DK;
#pragma unroll
            for (int pss = 0; pss < 8; pss++) {
                int w4 = t + pss * 256;          // float4 index 0..2047
                int row = w4 >> 5;
                int rem4 = w4 & 31;
                int kgx = rem4 >> 2;
                int ic = rem4 & 3;
                int dst = row * 128 + kgx * 16 + ((ic + kgx) & 3) * 4;
                float4 kv = *(const float4*)(ksrc + (long)w4 * 4);
                float4 qv = *(const float4*)(qsrc + (long)w4 * 4);
                *(float4*)&kt[dst] = kv;
                *(float4*)&qt[dst] = qv;
            }
            // ---- stage v (strided rows) ----
#pragma unroll
            for (int pss = 0; pss < 2; pss++) {
                int idx = t + pss * 256;         // 0..511
                int row = idx >> 3, c4 = idx & 7;
                float4 vv = *(const float4*)(vgl + (long)(ts0 + row) * DV + c4 * 4);
                *(float4*)&vt[row * 32 + c4 * 4] = vv;
            }
            // ---- stage eg, beta ----
            if (t < SCAN_T) et[t] = ep[ts0 + t];
            else if (t < 2 * SCAN_T) bts[t - SCAN_T] = bp[ts0 + t - SCAN_T];
        }
        __syncthreads();

        // ---- 64 steps, 2-step software pipeline of LDS fragment reads ----
        load_frag(KA, QA, 0);
        for (int lt = 0; lt < SCAN_T; lt += 2) {
            load_frag(KB, QB, lt + 1);
            step(KA, QA, lt, ts0 + lt);
            if (lt + 2 < SCAN_T) load_frag(KA, QA, lt + 2);
            step(KB, QB, lt + 1, ts0 + lt + 1);
        }
    }
}

// ---------------- gated RMS norm -> bf16 A2 ----------------------------------
__global__ __launch_bounds__(128) void gated_norm(
    const float* __restrict__ o, const u16* __restrict__ qkvz,
    const float* __restrict__ norm_w, u16* __restrict__ A2) {
    int bid = blockIdx.x;  // (b*L+l)*16 + h
    int t = threadIdx.x;   // 0..127
    float ov = o[(long)bid * 128 + t];
    float s = ov * ov;
#pragma unroll
    for (int off = 32; off > 0; off >>= 1) s += __shfl_down(s, off);
    __shared__ float ws2[2];
    if ((t & 63) == 0) ws2[t >> 6] = s;
    __syncthreads();
    float tot = ws2[0] + ws2[1];
    float rinv = rsqrtf(tot * (1.f / 128.f) + 1e-6f);
    int bl = bid >> 4, h = bid & 15;
    float z = bf2f(qkvz[(long)bl * NQKVZ + CONV_DIM + h * 128 + t]);
    float sig = 1.f / (1.f + expf(-z));
    float val = ov * rinv * norm_w[t] * sig;
    A2[(long)bl * 2048 + h * 128 + t] = f2bf(val);
}

// ---------------- host-side launcher -----------------------------------------
extern "C" void kernel_launch(void* const* d_in, const int* in_sizes, int n_in,
                              void* d_out, int out_size, void* d_ws, size_t ws_size,
                              hipStream_t stream) {
    const float* hs    = (const float*)d_in[0];  // (4,1024,2048)
    const float* Wqkvz = (const float*)d_in[1];  // (2048,8192)
    const float* Wba   = (const float*)d_in[2];  // (2048,32)
    const float* convw = (const float*)d_in[3];  // (6144,4)
    const float* convb = (const float*)d_in[4];  // (6144,)
    const float* A_log = (const float*)d_in[5];  // (16,)
    const float* dtb   = (const float*)d_in[6];  // (16,)
    const float* normw = (const float*)d_in[7];  // (128,)
    const float* Wout  = (const float*)d_in[8];  // (2048,2048)

    char* ws = (char*)d_ws;
    size_t off = 0;
    auto alloc = [&](size_t bytes) {
        size_t o = off;
        off = (off + bytes + 255) & ~(size_t)255;
        return o;
    };
    // region0: WqkvzT (bf16, 32MB) — dead after GEMM1, reused for os (fp32, 32MB)
    size_t r0 = alloc((size_t)NQKVZ * HID * 2);
    // region1: hs_bf16 (16MB) — dead after GEMM1, reused for A2 (bf16, 16MB)
    size_t r1 = alloc((size_t)4096 * HID * 2);
    u16*   WqkvzT = (u16*)(ws + r0);
    float* os     = (float*)(ws + r0);
    u16*   hsb    = (u16*)(ws + r1);
    u16*   A2     = (u16*)(ws + r1);
    u16*   qkvz   = (u16*)(ws + alloc((size_t)4096 * NQKVZ * 2));
    float* qs     = (float*)(ws + alloc((size_t)4096 * 2048 * 4));
    float* ks     = (float*)(ws + alloc((size_t)4096 * 2048 * 4));
    float* vs     = (float*)(ws + alloc((size_t)4096 * 2048 * 4));
    float* egs    = (float*)(ws + alloc((size_t)NB * NH * L_SEQ * 4));
    float* bs     = (float*)(ws + alloc((size_t)NB * NH * L_SEQ * 4));
    u16*   WoutT  = (u16*)(ws + alloc((size_t)HID * 2048 * 2));
    float* WbaT   = (float*)(ws + alloc((size_t)32 * HID * 4));

    // 1. convert + transposes (fp32 -> bf16 weights/activations)
    hipLaunchKernelGGL(f32_to_bf16, dim3(4096), dim3(256), 0, stream, hs, hsb);
    hipLaunchKernelGGL(transpose_f32_bf16, dim3(NQKVZ / 32, HID / 32), dim3(256), 0, stream,
                       Wqkvz, WqkvzT, HID, NQKVZ);
    hipLaunchKernelGGL(transpose_f32_bf16, dim3(2048 / 32, 2048 / 32), dim3(256), 0, stream,
                       Wout, WoutT, 2048, 2048);
    hipLaunchKernelGGL(transpose_f32_f32, dim3(1, HID / 32), dim3(256), 0, stream,
                       Wba, WbaT, HID, 32);

    // 2. big GEMM: qkvz = hs @ W_qkvz (bf16 in, bf16 out)
    hipLaunchKernelGGL((gemm_abT<u16>), dim3(NQKVZ / BN, 4096 / BM), dim3(256), 0, stream,
                       hsb, WqkvzT, qkvz, 4096, NQKVZ, HID);

    // 3. ba -> exp(g), beta (pure fp32)
    hipLaunchKernelGGL(ba_kernel, dim3(4096), dim3(64), 0, stream,
                       hs, WbaT, A_log, dtb, egs, bs);

    // 4. conv + l2norm -> q,k,v (fp32)
    hipLaunchKernelGGL(conv_qkv, dim3(4096), dim3(256), 0, stream,
                       qkvz, convw, convb, qs, ks, vs);

    // 5. scan (fp32, LDS-tiled, DPP-reduced)
    hipLaunchKernelGGL(gdn_scan, dim3(NB * NH * 4), dim3(256), 0, stream,
                       qs, ks, vs, egs, bs, os);

    // 6. gated RMS norm -> bf16 A2
    hipLaunchKernelGGL(gated_norm, dim3(4096 * NH), dim3(128), 0, stream,
                       os, qkvz, normw, A2);

    // 7. out = A2 @ W_out (bf16 in, fp32 out)
    hipLaunchKernelGGL((gemm_abT<float>), dim3(2048 / BN, 4096 / BM), dim3(256), 0, stream,
                       A2, WoutT, (float*)d_out, 4096, 2048, HID);
}

// Round 5
// 929.071 us; speedup vs baseline: 2.8431x; 1.0203x over previous
//
#include <hip/hip_runtime.h>

typedef unsigned short u16;
typedef unsigned int u32;
typedef short short8 __attribute__((ext_vector_type(8)));
typedef float float4v __attribute__((ext_vector_type(4)));

#define L_SEQ 1024
#define NB 4
#define NH 16
#define DK 128
#define DV 128
#define HID 2048
#define NQKVZ 8192
#define CONV_DIM 6144

static __device__ __forceinline__ float bf2f(u16 u) {
    union { u32 i; float f; } x; x.i = ((u32)u) << 16; return x.f;
}
static __device__ __forceinline__ u16 f2bf(float f) {
    union { float f; u32 u; } x; x.f = f;
    u32 r = x.u + 0x7FFF + ((x.u >> 16) & 1);
    return (u16)(r >> 16);
}

// DPP cross-lane adds (pure VALU, no DS).
#define DPP_ADD(x, ctrl) \
    ((x) + __int_as_float(__builtin_amdgcn_update_dpp( \
         0, __float_as_int(x), (ctrl), 0xF, 0xF, true)))
// Sum over 16 adjacent lanes (one DPP row). After xor1+xor2 quads are
// uniform, so row_half_mirror exchanges quad pairs and row_mirror exchanges
// the 8-lane halves — a full 16-lane reduction in 4 VALU ops.
static __device__ __forceinline__ float sum16_dpp(float x) {
    x = DPP_ADD(x, 0xB1);   // quad_perm [1,0,3,2]  = lane^1
    x = DPP_ADD(x, 0x4E);   // quad_perm [2,3,0,1]  = lane^2
    x = DPP_ADD(x, 0x141);  // row_half_mirror      = quad exchange within 8
    x = DPP_ADD(x, 0x140);  // row_mirror           = half exchange within 16
    return x;
}

// ---------------- fp32 -> bf16 elementwise convert ---------------------------
__global__ __launch_bounds__(256) void f32_to_bf16(
    const float* __restrict__ in, u16* __restrict__ out) {
    long i = ((long)blockIdx.x * 256 + threadIdx.x) * 8;
    float4 a = *(const float4*)(in + i);
    float4 b = *(const float4*)(in + i + 4);
    u16 tmp[8];
    tmp[0] = f2bf(a.x); tmp[1] = f2bf(a.y); tmp[2] = f2bf(a.z); tmp[3] = f2bf(a.w);
    tmp[4] = f2bf(b.x); tmp[5] = f2bf(b.y); tmp[6] = f2bf(b.z); tmp[7] = f2bf(b.w);
    *(uint4*)(out + i) = *(const uint4*)tmp;
}

// ---------------- transpose fp32 (RxC) -> bf16 (CxR) -------------------------
__global__ __launch_bounds__(256) void transpose_f32_bf16(
    const float* __restrict__ in, u16* __restrict__ out, int R, int C) {
    __shared__ float tile[32][33];
    int bx = blockIdx.x, by = blockIdx.y;
    int c = threadIdx.x & 31;
    int r0 = threadIdx.x >> 5;
#pragma unroll
    for (int i = 0; i < 4; i++) {
        int r = r0 + i * 8;
        tile[r][c] = in[(long)(by * 32 + r) * C + bx * 32 + c];
    }
    __syncthreads();
#pragma unroll
    for (int i = 0; i < 4; i++) {
        int r = r0 + i * 8;
        out[(long)(bx * 32 + r) * R + by * 32 + c] = f2bf(tile[c][r]);
    }
}

// ---------------- transpose fp32 (RxC) -> fp32 (CxR) -------------------------
__global__ __launch_bounds__(256) void transpose_f32_f32(
    const float* __restrict__ in, float* __restrict__ out, int R, int C) {
    __shared__ float tile[32][33];
    int bx = blockIdx.x, by = blockIdx.y;
    int c = threadIdx.x & 31;
    int r0 = threadIdx.x >> 5;
#pragma unroll
    for (int i = 0; i < 4; i++) {
        int r = r0 + i * 8;
        tile[r][c] = in[(long)(by * 32 + r) * C + bx * 32 + c];
    }
    __syncthreads();
#pragma unroll
    for (int i = 0; i < 4; i++) {
        int r = r0 + i * 8;
        out[(long)(bx * 32 + r) * R + by * 32 + c] = tile[c][r];
    }
}

// ---------------- GEMM: C[M,N] = A[M,K] * BT[N,K]^T, bf16 in, OutT out -------
#define BM 128
#define BN 128
#define BKK 32
#define LDT 40  // padded LDS row stride (elements)

static __device__ __forceinline__ void store_out(u16* p, float v)  { *p = f2bf(v); }
static __device__ __forceinline__ void store_out(float* p, float v){ *p = v; }

template <typename OutT>
__global__ __launch_bounds__(256) void gemm_abT(
    const u16* __restrict__ A, const u16* __restrict__ BT,
    OutT* __restrict__ C, int M, int N, int K) {
    __shared__ u16 As[BM * LDT];
    __shared__ u16 Bs[BN * LDT];
    int t = threadIdx.x;
    int lane = t & 63;
    int w = t >> 6;
    int wm = (w & 1) * 64;
    int wn = (w >> 1) * 64;
    int l15 = lane & 15;
    int quad = lane >> 4;
    long blockM = (long)blockIdx.y * BM;
    long blockN = (long)blockIdx.x * BN;

    float4v acc[4][4];
#pragma unroll
    for (int i = 0; i < 4; i++)
#pragma unroll
        for (int j = 0; j < 4; j++) acc[i][j] = (float4v){0.f, 0.f, 0.f, 0.f};

    int ar0 = t >> 2, ac0 = (t & 3) * 8;
    int ar1 = (t + 256) >> 2, ac1 = ((t + 256) & 3) * 8;

    const u16* Ab = A + blockM * K;
    const u16* Bb = BT + blockN * K;

    for (int k0 = 0; k0 < K; k0 += BKK) {
        uint4 av0 = *(const uint4*)(Ab + (long)ar0 * K + k0 + ac0);
        uint4 av1 = *(const uint4*)(Ab + (long)ar1 * K + k0 + ac1);
        uint4 bv0 = *(const uint4*)(Bb + (long)ar0 * K + k0 + ac0);
        uint4 bv1 = *(const uint4*)(Bb + (long)ar1 * K + k0 + ac1);
        __syncthreads();  // previous iteration's LDS reads done
        *(uint2*)(As + ar0 * LDT + ac0)     = make_uint2(av0.x, av0.y);
        *(uint2*)(As + ar0 * LDT + ac0 + 4) = make_uint2(av0.z, av0.w);
        *(uint2*)(As + ar1 * LDT + ac1)     = make_uint2(av1.x, av1.y);
        *(uint2*)(As + ar1 * LDT + ac1 + 4) = make_uint2(av1.z, av1.w);
        *(uint2*)(Bs + ar0 * LDT + ac0)     = make_uint2(bv0.x, bv0.y);
        *(uint2*)(Bs + ar0 * LDT + ac0 + 4) = make_uint2(bv0.z, bv0.w);
        *(uint2*)(Bs + ar1 * LDT + ac1)     = make_uint2(bv1.x, bv1.y);
        *(uint2*)(Bs + ar1 * LDT + ac1 + 4) = make_uint2(bv1.z, bv1.w);
        __syncthreads();

        union { short8 v; uint2 u[2]; } fa[4], fb[4];
#pragma unroll
        for (int i = 0; i < 4; i++) {
            const u16* pa = As + (wm + i * 16 + l15) * LDT + quad * 8;
            fa[i].u[0] = *(const uint2*)pa;
            fa[i].u[1] = *(const uint2*)(pa + 4);
            const u16* pb = Bs + (wn + i * 16 + l15) * LDT + quad * 8;
            fb[i].u[0] = *(const uint2*)pb;
            fb[i].u[1] = *(const uint2*)(pb + 4);
        }
#pragma unroll
        for (int i = 0; i < 4; i++)
#pragma unroll
            for (int j = 0; j < 4; j++)
                acc[i][j] = __builtin_amdgcn_mfma_f32_16x16x32_bf16(
                    fa[i].v, fb[j].v, acc[i][j], 0, 0, 0);
    }

#pragma unroll
    for (int i = 0; i < 4; i++) {
        long mrow = blockM + wm + i * 16 + quad * 4;
#pragma unroll
        for (int j = 0; j < 4; j++) {
            long col = blockN + wn + j * 16 + l15;
#pragma unroll
            for (int r = 0; r < 4; r++) {
                store_out(&C[(mrow + r) * N + col], acc[i][j][r]);
            }
        }
    }
}

// ---------------- ba: eg = exp(g), beta = sigmoid(b) -------------------------
__global__ __launch_bounds__(64) void ba_kernel(
    const float* __restrict__ hs, const float* __restrict__ WbaT,
    const float* __restrict__ A_log, const float* __restrict__ dt_bias,
    float* __restrict__ egout, float* __restrict__ bout) {
    int bl = blockIdx.x;  // b*L + l
    int b = bl >> 10, l = bl & 1023;
    int t = threadIdx.x;
    __shared__ __align__(16) float hb[HID];
    const float* hrow = hs + (long)bl * HID;
#pragma unroll
    for (int i = 0; i < 8; i++) {
        int idx = (t + i * 64) * 4;
        *(float4*)(hb + idx) = *(const float4*)(hrow + idx);
    }
    __syncthreads();
    int n = t & 31, hf = t >> 5;
    const float* wrow = WbaT + (long)n * HID + hf * 1024;
    const float* hp = hb + hf * 1024;
    float acc = 0.f;
    for (int i = 0; i < 1024; i += 4) {
        float4 wv = *(const float4*)(wrow + i);
        float4 hv = *(const float4*)(hp + i);
        acc += wv.x * hv.x + wv.y * hv.y + wv.z * hv.z + wv.w * hv.w;
    }
    acc += __shfl_down(acc, 32);
    if (t < 32) {
        if (n < 16) {
            bout[((long)(b * NH + n)) * L_SEQ + l] = 1.f / (1.f + expf(-acc));
        } else {
            int h = n - 16;
            float x = acc + dt_bias[h];
            float sp = (x > 20.f) ? x : log1pf(expf(x));
            egout[((long)(b * NH + h)) * L_SEQ + l] = expf(-expf(A_log[h]) * sp);
        }
    }
}

// ---------------- conv(KS=4 causal depthwise) + l2norm(q,k) + split v --------
__global__ __launch_bounds__(256) void conv_qkv(
    const u16* __restrict__ qkvz, const float* __restrict__ conv_w,
    const float* __restrict__ conv_b,
    float* __restrict__ qs, float* __restrict__ ks, float* __restrict__ vs) {
    int bl = blockIdx.x;  // b*L + l
    int b = bl >> 10, l = bl & 1023;
    int t = threadIdx.x;
    __shared__ float xb[CONV_DIM];
    __shared__ float red[32][9];
    __shared__ float rbuf[32];

    for (int c = t; c < CONV_DIM; c += 256) {
        float acc = conv_b[c];
        float w0 = conv_w[c * 4 + 0];
        float w1 = conv_w[c * 4 + 1];
        float w2 = conv_w[c * 4 + 2];
        float w3 = conv_w[c * 4 + 3];
        long rowbase = (long)(b * L_SEQ) * NQKVZ + c;
        if (l - 3 >= 0) acc += bf2f(qkvz[rowbase + (long)(l - 3) * NQKVZ]) * w0;
        if (l - 2 >= 0) acc += bf2f(qkvz[rowbase + (long)(l - 2) * NQKVZ]) * w1;
        if (l - 1 >= 0) acc += bf2f(qkvz[rowbase + (long)(l - 1) * NQKVZ]) * w2;
        acc += bf2f(qkvz[rowbase + (long)l * NQKVZ]) * w3;
        xb[c] = acc;
    }
    __syncthreads();
    {
        int grp = t >> 3;   // 0..31 (q heads 0..15, k heads 16..31)
        int j8 = t & 7;
        float s = 0.f;
#pragma unroll
        for (int i = 0; i < 16; i++) {
            float xv = xb[grp * 128 + j8 * 16 + i];
            s += xv * xv;
        }
        red[grp][j8] = s;
    }
    __syncthreads();
    if (t < 32) {
        float s = 0.f;
#pragma unroll
        for (int i = 0; i < 8; i++) s += red[t][i];
        rbuf[t] = rsqrtf(s + 1e-6f);
    }
    __syncthreads();
    for (int c = t; c < CONV_DIM; c += 256) {
        float xv = xb[c];
        if (c < 2048) {
            int h = c >> 7, d = c & 127;
            qs[(((long)(b * NH + h)) * L_SEQ + l) * DK + d] = xv * rbuf[h];
        } else if (c < 4096) {
            int c2 = c - 2048;
            int h = c2 >> 7, d = c2 & 127;
            ks[(((long)(b * NH + h)) * L_SEQ + l) * DK + d] = xv * rbuf[16 + h];
        } else {
            int c2 = c - 4096;
            int h = c2 >> 7, d = c2 & 127;
            vs[(((long)(b * NH + h)) * L_SEQ + l) * DV + d] = xv;
        }
    }
}

// ---------------- sequential gated delta scan, v5 ----------------------------
// 512 blocks = bh(64) x dc(8, 16 d-cols each) -> 2 blocks/CU, 8 waves/CU.
// 256 threads: kg = lane&15 (8 k each), d-col = wave*4 + (lane>>4).
// LDS: 64-step k/q tiles, XOR-swizzled at float4-slot granularity
// (phys = slot ^ (slot>>3)) -> fragment reads are exactly 2-way (free).
// k-reduction = 4 DPP adds over the 16-lane row. All arrays const-indexed.
#define SCAN_T 64

union F8u { float4 v4[2]; float f[8]; };

__global__ __launch_bounds__(256) void gdn_scan(
    const float* __restrict__ q, const float* __restrict__ k,
    const float* __restrict__ v, const float* __restrict__ eg,
    const float* __restrict__ beta, float* __restrict__ o) {
    int bid = blockIdx.x;
    int dc = bid & 7;
    int bh = bid >> 3;          // b*NH + h
    int b = bh >> 4, h = bh & 15;
    int t = threadIdx.x;
    int lane = t & 63;
    int wv = t >> 6;            // wave 0..3
    int kg = lane & 15;         // 8 k values per thread
    int dl = wv * 4 + (lane >> 4);  // 0..15
    int d = dc * 16 + dl;

    __shared__ float kt[SCAN_T * 128];
    __shared__ float qt[SCAN_T * 128];
    __shared__ float vt[SCAN_T * 16];
    __shared__ float et[SCAN_T];
    __shared__ float bts[SCAN_T];

    const long base = (long)bh * L_SEQ;
    const float* kgl = k + base * DK;
    const float* qgl = q + base * DK;
    const float* vgl = v + base * DV + dc * 16;
    const float* ep  = eg + base;
    const float* bp  = beta + base;
    const float scale = 0.08838834764831845f;  // 128^-0.5

    float S[8];
#pragma unroll
    for (int j = 0; j < 8; j++) S[j] = 0.f;

    // swizzled float4-slot indices for this thread's k-fragment
    const int slot0 = kg * 2;
    const int slot1 = kg * 2 + 1;
    const int phys0 = (slot0 ^ (slot0 >> 3)) * 4;  // float offset
    const int phys1 = (slot1 ^ (slot1 >> 3)) * 4;

    F8u KA, QA, KB, QB;

    auto load_frag = [&](F8u& KF, F8u& QF, int lt) {
        int rb = lt * 128;
        KF.v4[0] = *(const float4*)&kt[rb + phys0];
        KF.v4[1] = *(const float4*)&kt[rb + phys1];
        QF.v4[0] = *(const float4*)&qt[rb + phys0];
        QF.v4[1] = *(const float4*)&qt[rb + phys1];
    };

    auto step = [&](const F8u& KF, const F8u& QF, int lt, int abs_ts) {
        float e = et[lt];
        float btv = bts[lt];
        float vval = vt[lt * 16 + dl];
        float pr[8];
#pragma unroll
        for (int j = 0; j < 8; j++) {
            S[j] *= e;
            pr[j] = KF.f[j] * S[j];
        }
        float p = ((pr[0] + pr[1]) + (pr[2] + pr[3])) +
                  ((pr[4] + pr[5]) + (pr[6] + pr[7]));
        p = sum16_dpp(p);
        float delta = (vval - p) * btv;
        float orr[8];
#pragma unroll
        for (int j = 0; j < 8; j++) {
            S[j] = fmaf(KF.f[j], delta, S[j]);
            orr[j] = QF.f[j] * S[j];
        }
        float oo = ((orr[0] + orr[1]) + (orr[2] + orr[3])) +
                   ((orr[4] + orr[5]) + (orr[6] + orr[7]));
        oo = sum16_dpp(oo);
        if (kg == 0) {
            o[(((long)(b * L_SEQ + abs_ts)) * NH + h) * DV + d] = oo * scale;
        }
    };

    for (int ts0 = 0; ts0 < L_SEQ; ts0 += SCAN_T) {
        __syncthreads();  // prior tile's LDS reads complete
        // ---- stage k, q: linear global float4 -> swizzled LDS slot ----
        {
            const float* ksrc = kgl + (long)ts0 * DK;
            const float* qsrc = qgl + (long)ts0 * DK;
#pragma unroll
            for (int pss = 0; pss < 8; pss++) {
                int w4 = t + pss * 256;          // float4 index 0..2047
                int row = w4 >> 5;
                int slot = w4 & 31;
                int dst = row * 128 + (slot ^ (slot >> 3)) * 4;
                float4 kv = *(const float4*)(ksrc + (long)w4 * 4);
                float4 qv = *(const float4*)(qsrc + (long)w4 * 4);
                *(float4*)&kt[dst] = kv;
                *(float4*)&qt[dst] = qv;
            }
            // ---- stage v (16 floats per timestep row) ----
            {
                int row = t >> 2, c4 = t & 3;    // 256 threads = 64 rows x 4
                float4 vv = *(const float4*)(vgl + (long)(ts0 + row) * DV + c4 * 4);
                *(float4*)&vt[row * 16 + c4 * 4] = vv;
            }
            // ---- stage eg, beta ----
            if (t < SCAN_T) et[t] = ep[ts0 + t];
            else if (t < 2 * SCAN_T) bts[t - SCAN_T] = bp[ts0 + t - SCAN_T];
        }
        __syncthreads();

        // ---- 64 steps, 2-step software pipeline of LDS fragment reads ----
        load_frag(KA, QA, 0);
        for (int lt = 0; lt < SCAN_T; lt += 2) {
            load_frag(KB, QB, lt + 1);
            step(KA, QA, lt, ts0 + lt);
            if (lt + 2 < SCAN_T) load_frag(KA, QA, lt + 2);
            step(KB, QB, lt + 1, ts0 + lt + 1);
        }
    }
}

// ---------------- gated RMS norm -> bf16 A2 ----------------------------------
__global__ __launch_bounds__(128) void gated_norm(
    const float* __restrict__ o, const u16* __restrict__ qkvz,
    const float* __restrict__ norm_w, u16* __restrict__ A2) {
    int bid = blockIdx.x;  // (b*L+l)*16 + h
    int t = threadIdx.x;   // 0..127
    float ov = o[(long)bid * 128 + t];
    float s = ov * ov;
#pragma unroll
    for (int off = 32; off > 0; off >>= 1) s += __shfl_down(s, off);
    __shared__ float ws2[2];
    if ((t & 63) == 0) ws2[t >> 6] = s;
    __syncthreads();
    float tot = ws2[0] + ws2[1];
    float rinv = rsqrtf(tot * (1.f / 128.f) + 1e-6f);
    int bl = bid >> 4, h = bid & 15;
    float z = bf2f(qkvz[(long)bl * NQKVZ + CONV_DIM + h * 128 + t]);
    float sig = 1.f / (1.f + expf(-z));
    float val = ov * rinv * norm_w[t] * sig;
    A2[(long)bl * 2048 + h * 128 + t] = f2bf(val);
}

// ---------------- host-side launcher -----------------------------------------
extern "C" void kernel_launch(void* const* d_in, const int* in_sizes, int n_in,
                              void* d_out, int out_size, void* d_ws, size_t ws_size,
                              hipStream_t stream) {
    const float* hs    = (const float*)d_in[0];  // (4,1024,2048)
    const float* Wqkvz = (const float*)d_in[1];  // (2048,8192)
    const float* Wba   = (const float*)d_in[2];  // (2048,32)
    const float* convw = (const float*)d_in[3];  // (6144,4)
    const float* convb = (const float*)d_in[4];  // (6144,)
    const float* A_log = (const float*)d_in[5];  // (16,)
    const float* dtb   = (const float*)d_in[6];  // (16,)
    const float* normw = (const float*)d_in[7];  // (128,)
    const float* Wout  = (const float*)d_in[8];  // (2048,2048)

    char* ws = (char*)d_ws;
    size_t off = 0;
    auto alloc = [&](size_t bytes) {
        size_t o = off;
        off = (off + bytes + 255) & ~(size_t)255;
        return o;
    };
    // region0: WqkvzT (bf16, 32MB) — dead after GEMM1, reused for os (fp32, 32MB)
    size_t r0 = alloc((size_t)NQKVZ * HID * 2);
    // region1: hs_bf16 (16MB) — dead after GEMM1, reused for A2 (bf16, 16MB)
    size_t r1 = alloc((size_t)4096 * HID * 2);
    u16*   WqkvzT = (u16*)(ws + r0);
    float* os     = (float*)(ws + r0);
    u16*   hsb    = (u16*)(ws + r1);
    u16*   A2     = (u16*)(ws + r1);
    u16*   qkvz   = (u16*)(ws + alloc((size_t)4096 * NQKVZ * 2));
    float* qs     = (float*)(ws + alloc((size_t)4096 * 2048 * 4));
    float* ks     = (float*)(ws + alloc((size_t)4096 * 2048 * 4));
    float* vs     = (float*)(ws + alloc((size_t)4096 * 2048 * 4));
    float* egs    = (float*)(ws + alloc((size_t)NB * NH * L_SEQ * 4));
    float* bs     = (float*)(ws + alloc((size_t)NB * NH * L_SEQ * 4));
    u16*   WoutT  = (u16*)(ws + alloc((size_t)HID * 2048 * 2));
    float* WbaT   = (float*)(ws + alloc((size_t)32 * HID * 4));

    // 1. convert + transposes (fp32 -> bf16 weights/activations)
    hipLaunchKernelGGL(f32_to_bf16, dim3(4096), dim3(256), 0, stream, hs, hsb);
    hipLaunchKernelGGL(transpose_f32_bf16, dim3(NQKVZ / 32, HID / 32), dim3(256), 0, stream,
                       Wqkvz, WqkvzT, HID, NQKVZ);
    hipLaunchKernelGGL(transpose_f32_bf16, dim3(2048 / 32, 2048 / 32), dim3(256), 0, stream,
                       Wout, WoutT, 2048, 2048);
    hipLaunchKernelGGL(transpose_f32_f32, dim3(1, HID / 32), dim3(256), 0, stream,
                       Wba, WbaT, HID, 32);

    // 2. big GEMM: qkvz = hs @ W_qkvz (bf16 in, bf16 out)
    hipLaunchKernelGGL((gemm_abT<u16>), dim3(NQKVZ / BN, 4096 / BM), dim3(256), 0, stream,
                       hsb, WqkvzT, qkvz, 4096, NQKVZ, HID);

    // 3. ba -> exp(g), beta (pure fp32)
    hipLaunchKernelGGL(ba_kernel, dim3(4096), dim3(64), 0, stream,
                       hs, WbaT, A_log, dtb, egs, bs);

    // 4. conv + l2norm -> q,k,v (fp32)
    hipLaunchKernelGGL(conv_qkv, dim3(4096), dim3(256), 0, stream,
                       qkvz, convw, convb, qs, ks, vs);

    // 5. scan (fp32, LDS-tiled, DPP-reduced, 512 blocks)
    hipLaunchKernelGGL(gdn_scan, dim3(NB * NH * 8), dim3(256), 0, stream,
                       qs, ks, vs, egs, bs, os);

    // 6. gated RMS norm -> bf16 A2
    hipLaunchKernelGGL(gated_norm, dim3(4096 * NH), dim3(128), 0, stream,
                       os, qkvz, normw, A2);

    // 7. out = A2 @ W_out (bf16 in, fp32 out)
    hipLaunchKernelGGL((gemm_abT<float>), dim3(2048 / BN, 4096 / BM), dim3(256), 0, stream,
                       A2, WoutT, (float*)d_out, 4096, 2048, HID);
}